// Round 1
// 308.829 us; speedup vs baseline: 1.0028x; 1.0028x over previous
//
#include <hip/hip_runtime.h>
#include <stdint.h>

#define T_LEN 200
#define B_SZ  1024
#define D_DIM 128
#define LOG2E 1.44269504088896340736f

typedef __bf16 bf16_t;
typedef __bf16 bf16x8 __attribute__((ext_vector_type(8)));
typedef float  f32x4  __attribute__((ext_vector_type(4)));

union BF8 { bf16x8 v; bf16_t e[8]; };

// RNE fp32->bf16 pack of two values into one dword
__device__ inline uint32_t pk_bf16(float a, float b) {
  uint32_t ua = __float_as_uint(a), ub = __float_as_uint(b);
  ua += 0x7fffu + ((ua >> 16) & 1u);
  ub += 0x7fffu + ((ub >> 16) & 1u);
  return (ua >> 16) | (ub & 0xffff0000u);
}
__device__ inline float rcp_f(float x) { return __builtin_amdgcn_rcpf(x); }

// LDS-only barrier: wait LDS ops, leave global loads (vmcnt) in flight.
#define BAR_LDS() asm volatile("s_waitcnt lgkmcnt(0)\n\ts_barrier" ::: "memory")

// ---------------------------------------------------------------------------
// Fused AUGRU scan, software-pipelined x-side.
// 64 blocks x 512 threads; block bb owns batch rows [16*bb, 16*bb+16).
// Round-1 serial-path fixes:
//  (A) am(t+1) LDS prefetch issued at TOP of step (was right before barrier:
//      its ~120cy latency sat inside the lgkmcnt(0) drain on the critical path)
//  (B) all 8 fragment ds_reads issue first after the barrier (state frags
//      before x frags); staging pack VALU now fills the read-latency window
//  (C) state-side MFMA chains split 4-deep -> two independent 2-chains + add
//      (halves accumulator-dependency latency); state MFMAs issue before
//      x-side MFMAs
// LDS layouts (halfword index):
//   xb: slot(row,k) = (k>>3)*128 + row*8 + (k&7)           (frag = 8*l)
//   sb: slot(row,k) = (k>>3)*128 + (row^(2*((k>>3)&1)))*8 + (k&7)
//       reader frag = 8*(l ^ 2*(lg&1)); writer slots wbase + 8*(i^psi)
// ---------------------------------------------------------------------------
__global__ __launch_bounds__(512, 2) void augru_fused(
    const float* __restrict__ x,
    const float* __restrict__ state,
    const float* __restrict__ att,
    const float* __restrict__ mask,
    const float* __restrict__ Wau, const float* __restrict__ bau,
    const float* __restrict__ Wbu,
    const float* __restrict__ War, const float* __restrict__ bar,
    const float* __restrict__ Wbr,
    const float* __restrict__ Wac, const float* __restrict__ bac,
    const float* __restrict__ Wbc,
    float* __restrict__ out)
{
  __shared__ bf16_t xb[2][2048];         // x tiles (bf16, frag-linear)
  __shared__ bf16_t sb[2][2048];         // state ping-pong (bf16, swizzled)
  __shared__ float  am_lds[T_LEN * 16];  // att*mask fused, [t][row]

  const int tid = threadIdx.x;
  const int w  = tid >> 6;
  const int l  = tid & 63;
  const int lm = l & 15;
  const int lg = l >> 4;
  const int bb = blockIdx.x;
  const int R0 = bb * 16;
  const int col = w * 16 + lm;

  // --- weight B-fragments in registers (pre-scaled: u,r by log2e; c by 2log2e)
  BF8 xu[4], xr[4], xc[4];   // x-side  (Wau, War, Wac)
  BF8 su[4], sr[4], sc[4];   // state-side (Wbu, Wbr, Wbc)
#pragma unroll
  for (int kk = 0; kk < 4; ++kk) {
#pragma unroll
    for (int j = 0; j < 8; ++j) {
      int k = kk * 32 + lg * 8 + j;
      xu[kk].e[j] = (bf16_t)(Wau[k * 128 + col] * LOG2E);
      xr[kk].e[j] = (bf16_t)(War[k * 128 + col] * LOG2E);
      xc[kk].e[j] = (bf16_t)(Wac[k * 128 + col] * (2.0f * LOG2E));
      su[kk].e[j] = (bf16_t)(Wbu[k * 128 + col] * LOG2E);
      sr[kk].e[j] = (bf16_t)(Wbr[k * 128 + col] * LOG2E);
      sc[kk].e[j] = (bf16_t)(Wbc[k * 128 + col] * (2.0f * LOG2E));
    }
  }
  const float b_u = bau[col] * LOG2E;
  const float b_r = bar[col] * LOG2E;
  const float b_c = bac[col] * (2.0f * LOG2E);

  // --- att*mask preload
  for (int idx = tid; idx < T_LEN * 16; idx += 512) {
    int t = idx >> 4, row = idx & 15;
    am_lds[idx] = att[t * B_SZ + R0 + row] * mask[(R0 + row) * T_LEN + t];
  }

  // --- fp32 state in registers: lane owns (row = lg*4+i, col)
  float sreg[4];
#pragma unroll
  for (int i = 0; i < 4; ++i)
    sreg[i] = state[(R0 + lg * 4 + i) * 128 + col];

  // state bf16 into sb[0], swizzled layout
  for (int idx = tid; idx < 2048; idx += 512) {
    int row = idx >> 7, k = idx & 127;
    sb[0][(k >> 3) * 128 + (row ^ (2 * ((k >> 3) & 1))) * 8 + (k & 7)] =
        (bf16_t)state[(R0 + row) * 128 + k];
  }

  // --- x staging: thread tid stages row=tid&15, float4 chunk sc4=tid>>4
  const int srow = tid & 15;
  const int sc4  = tid >> 4;
  const int stg_pos = (sc4 >> 1) * 128 + srow * 8 + (sc4 & 1) * 4;  // halfwords
  const float* xrow = x + (size_t)(R0 + srow) * 128 + sc4 * 4;
  const size_t xstep = (size_t)B_SZ * 128;

  // prologue: stage x(0), x(1); register-prefetch x(2..4)
  {
    float4 v0 = *(const float4*)(xrow);
    float4 v1 = *(const float4*)(xrow + xstep);
    uint2 p0; p0.x = pk_bf16(v0.x, v0.y); p0.y = pk_bf16(v0.z, v0.w);
    uint2 p1; p1.x = pk_bf16(v1.x, v1.y); p1.y = pk_bf16(v1.z, v1.w);
    *(uint2*)&xb[0][stg_pos] = p0;
    *(uint2*)&xb[1][stg_pos] = p1;
  }
  float4 xq0 = *(const float4*)(xrow + 2 * xstep);
  float4 xq1 = *(const float4*)(xrow + 3 * xstep);
  float4 xq2 = *(const float4*)(xrow + 4 * xstep);

  __syncthreads();   // full drain once

  // x-gates(0) from xb[0] into registers
  f32x4 gU = {b_u, b_u, b_u, b_u};
  f32x4 gR = {b_r, b_r, b_r, b_r};
  f32x4 gC = {b_c, b_c, b_c, b_c};
  {
    bf16x8 ax[4];
#pragma unroll
    for (int kk = 0; kk < 4; ++kk)
      ax[kk] = *(const bf16x8*)&xb[0][kk * 512 + 8 * l];
#pragma unroll
    for (int kk = 0; kk < 4; ++kk) {
      gU = __builtin_amdgcn_mfma_f32_16x16x32_bf16(ax[kk], xu[kk].v, gU, 0, 0, 0);
      gR = __builtin_amdgcn_mfma_f32_16x16x32_bf16(ax[kk], xr[kk].v, gR, 0, 0, 0);
      gC = __builtin_amdgcn_mfma_f32_16x16x32_bf16(ax[kk], xc[kk].v, gC, 0, 0, 0);
    }
  }
  union F4 { float4 v; float e[4]; } amv, amn;
  amv.v = *(const float4*)&am_lds[lg * 4];           // am(0)

  const int lx8   = 8 * (l ^ (2 * (lg & 1)));        // swizzled sb frag offset
  const int psi   = 2 * ((col >> 3) & 1);            // writer value permutation
  const int wbase = (col >> 3) * 128 + lg * 32 + (col & 7);

  BAR_LDS();   // protect xb[0] before step 0 overwrites it

  auto step = [&](int t) {
    const int rp = t & 1;

    // (B) fragment ds_reads issue FIRST: state frags s(t), then x frags x(t+1)
    bf16x8 as_[4], ax[4];
#pragma unroll
    for (int kk = 0; kk < 4; ++kk)
      as_[kk] = *(const bf16x8*)&sb[rp][kk * 512 + lx8];
#pragma unroll
    for (int kk = 0; kk < 4; ++kk)
      ax[kk]  = *(const bf16x8*)&xb[rp ^ 1][kk * 512 + 8 * l];

    // (A) am(t+1) prefetch issued EARLY so it drains long before the barrier
    int ta = t + 1; if (ta > T_LEN - 1) ta = T_LEN - 1;
    amn.v = *(const float4*)&am_lds[ta * 16 + lg * 4];

    // stage x(t+2) into xb[rp]; pack VALU fills the ds_read latency window
    {
      uint2 p; p.x = pk_bf16(xq0.x, xq0.y); p.y = pk_bf16(xq0.z, xq0.w);
      *(uint2*)&xb[rp][stg_pos] = p;
    }
    xq0 = xq1; xq1 = xq2;
    int tl = t + 5; if (tl > T_LEN - 1) tl = T_LEN - 1;
    xq2 = *(const float4*)(xrow + (size_t)tl * xstep);

    // (C) state-side MFMAs first, each gate as two independent 2-chains
    f32x4 aU = gU, aR = gR;
    f32x4 bC  = {0.f, 0.f, 0.f, 0.f};
    f32x4 aU2 = {0.f, 0.f, 0.f, 0.f};
    f32x4 aR2 = {0.f, 0.f, 0.f, 0.f};
    f32x4 bC2 = {0.f, 0.f, 0.f, 0.f};
    aU  = __builtin_amdgcn_mfma_f32_16x16x32_bf16(as_[0], su[0].v, aU,  0, 0, 0);
    aR  = __builtin_amdgcn_mfma_f32_16x16x32_bf16(as_[0], sr[0].v, aR,  0, 0, 0);
    bC  = __builtin_amdgcn_mfma_f32_16x16x32_bf16(as_[0], sc[0].v, bC,  0, 0, 0);
    aU2 = __builtin_amdgcn_mfma_f32_16x16x32_bf16(as_[2], su[2].v, aU2, 0, 0, 0);
    aR2 = __builtin_amdgcn_mfma_f32_16x16x32_bf16(as_[2], sr[2].v, aR2, 0, 0, 0);
    bC2 = __builtin_amdgcn_mfma_f32_16x16x32_bf16(as_[2], sc[2].v, bC2, 0, 0, 0);
    aU  = __builtin_amdgcn_mfma_f32_16x16x32_bf16(as_[1], su[1].v, aU,  0, 0, 0);
    aR  = __builtin_amdgcn_mfma_f32_16x16x32_bf16(as_[1], sr[1].v, aR,  0, 0, 0);
    bC  = __builtin_amdgcn_mfma_f32_16x16x32_bf16(as_[1], sc[1].v, bC,  0, 0, 0);
    aU2 = __builtin_amdgcn_mfma_f32_16x16x32_bf16(as_[3], su[3].v, aU2, 0, 0, 0);
    aR2 = __builtin_amdgcn_mfma_f32_16x16x32_bf16(as_[3], sr[3].v, aR2, 0, 0, 0);
    bC2 = __builtin_amdgcn_mfma_f32_16x16x32_bf16(as_[3], sc[3].v, bC2, 0, 0, 0);

    // x-side gates for t+1 (off critical path, issue after state side)
    f32x4 nU = {b_u, b_u, b_u, b_u};
    f32x4 nR = {b_r, b_r, b_r, b_r};
    f32x4 nC = {b_c, b_c, b_c, b_c};
#pragma unroll
    for (int kk = 0; kk < 4; ++kk) {
      nU = __builtin_amdgcn_mfma_f32_16x16x32_bf16(ax[kk], xu[kk].v, nU, 0, 0, 0);
      nR = __builtin_amdgcn_mfma_f32_16x16x32_bf16(ax[kk], xr[kk].v, nR, 0, 0, 0);
      nC = __builtin_amdgcn_mfma_f32_16x16x32_bf16(ax[kk], xc[kk].v, nC, 0, 0, 0);
    }

    // combine split accumulators
    aU = aU + aU2;
    aR = aR + aR2;
    bC = bC + bC2;

    bf16_t* wbuf = sb[rp ^ 1];
#pragma unroll
    for (int i = 0; i < 4; ++i) {
      float u  = rcp_f(1.0f + __builtin_amdgcn_exp2f(-aU[i]));
      float r  = rcp_f(1.0f + __builtin_amdgcn_exp2f(-aR[i]));
      float wc = fmaf(r, bC[i], gC[i]);
      float cg = fmaf(-2.0f, rcp_f(__builtin_amdgcn_exp2f(wc) + 1.0f), 1.0f);
      float sf = fmaf(amv.e[i] * u, cg - sreg[i], sreg[i]);
      sreg[i] = sf;
      wbuf[wbase + 8 * (i ^ psi)] = (bf16_t)sf;
    }

    // rotate pipelined registers
    gU = nU; gR = nR; gC = nC;
    amv.v = amn.v;

    BAR_LDS();
  };

#pragma unroll 1
  for (int t = 0; t < T_LEN; t += 2) {
    step(t);
    step(t + 1);
  }

#pragma unroll
  for (int i = 0; i < 4; ++i)
    out[(R0 + lg * 4 + i) * 128 + col] = sreg[i];
}

// ---------------------------------------------------------------------------
extern "C" void kernel_launch(void* const* d_in, const int* in_sizes, int n_in,
                              void* d_out, int out_size, void* d_ws, size_t ws_size,
                              hipStream_t stream)
{
  const float* x    = (const float*)d_in[0];
  const float* st   = (const float*)d_in[1];
  const float* att  = (const float*)d_in[2];
  const float* mask = (const float*)d_in[3];
  // d_in[4] = max_len (unused; shapes hard-coded)
  const float* Wau  = (const float*)d_in[5];
  const float* bau  = (const float*)d_in[6];
  const float* Wbu  = (const float*)d_in[7];
  const float* War  = (const float*)d_in[8];
  const float* bar  = (const float*)d_in[9];
  const float* Wbr  = (const float*)d_in[10];
  const float* Wac  = (const float*)d_in[11];
  const float* bac  = (const float*)d_in[12];
  const float* Wbc  = (const float*)d_in[13];

  (void)d_ws; (void)ws_size;

  augru_fused<<<dim3(64), dim3(512), 0, stream>>>(
      x, st, att, mask, Wau, bau, Wbu, War, bar, Wbr, Wac, bac, Wbc,
      (float*)d_out);
}

// Round 2
// 290.645 us; speedup vs baseline: 1.0655x; 1.0626x over previous
//
#include <hip/hip_runtime.h>
#include <stdint.h>

#define T_LEN 200
#define B_SZ  1024
#define D_DIM 128
#define LOG2E 1.44269504088896340736f

typedef __bf16 bf16_t;
typedef __bf16 bf16x8 __attribute__((ext_vector_type(8)));
typedef float  f32x4  __attribute__((ext_vector_type(4)));

union BF8 { bf16x8 v; bf16_t e[8]; };

// RNE fp32->bf16 pack of two values into one dword
__device__ inline uint32_t pk_bf16(float a, float b) {
  uint32_t ua = __float_as_uint(a), ub = __float_as_uint(b);
  ua += 0x7fffu + ((ua >> 16) & 1u);
  ub += 0x7fffu + ((ub >> 16) & 1u);
  return (ua >> 16) | (ub & 0xffff0000u);
}
__device__ inline float rcp_f(float x) { return __builtin_amdgcn_rcpf(x); }

// LDS-only barrier: wait LDS ops, leave global loads (vmcnt) in flight.
#define BAR_LDS() asm volatile("s_waitcnt lgkmcnt(0)\n\ts_barrier" ::: "memory")

// ---------------------------------------------------------------------------
// Fused AUGRU scan, software-pipelined x-side.
// 64 blocks x 512 threads; block bb owns batch rows [16*bb, 16*bb+16).
// Round-2: instruction diet (step is ISSUE-bound, ~950 cy/SIMD/step):
//  - reverted round-1 (C) chain split (cost 24 instrs/wave, latency saving
//    was not on the critical path) -> round-0 4-deep interleaved chains,
//    restoring the exact summation order of the passing baseline
//  - x prefetch: 2 static register buffers at distance 4, renamed by the
//    2-step unroll -> no per-step float4 rotation movs; prefetch offset is
//    a uniform scalar (s_min/s_add) instead of per-step v_mul+clamp
//  - am_lds padded to 201 rows + walking pointer -> no per-step clamp
// Kept from round-1: frag ds_reads issue first (state then x), am prefetch
// early, state-side MFMAs before x-side.
// LDS layouts (halfword index):
//   xb: slot(row,k) = (k>>3)*128 + row*8 + (k&7)           (frag = 8*l)
//   sb: slot(row,k) = (k>>3)*128 + (row^(2*((k>>3)&1)))*8 + (k&7)
//       reader frag = 8*(l ^ 2*(lg&1)); writer slots wbase + 8*(i^psi)
// ---------------------------------------------------------------------------
__global__ __launch_bounds__(512, 2) void augru_fused(
    const float* __restrict__ x,
    const float* __restrict__ state,
    const float* __restrict__ att,
    const float* __restrict__ mask,
    const float* __restrict__ Wau, const float* __restrict__ bau,
    const float* __restrict__ Wbu,
    const float* __restrict__ War, const float* __restrict__ bar,
    const float* __restrict__ Wbr,
    const float* __restrict__ Wac, const float* __restrict__ bac,
    const float* __restrict__ Wbc,
    float* __restrict__ out)
{
  __shared__ bf16_t xb[2][2048];           // x tiles (bf16, frag-linear)
  __shared__ bf16_t sb[2][2048];           // state ping-pong (bf16, swizzled)
  __shared__ float  am_lds[(T_LEN + 1) * 16];  // att*mask fused, [t][row], +1 pad row

  const int tid = threadIdx.x;
  const int w  = tid >> 6;
  const int l  = tid & 63;
  const int lm = l & 15;
  const int lg = l >> 4;
  const int bb = blockIdx.x;
  const int R0 = bb * 16;
  const int col = w * 16 + lm;

  // --- weight B-fragments in registers (pre-scaled: u,r by log2e; c by 2log2e)
  BF8 xu[4], xr[4], xc[4];   // x-side  (Wau, War, Wac)
  BF8 su[4], sr[4], sc[4];   // state-side (Wbu, Wbr, Wbc)
#pragma unroll
  for (int kk = 0; kk < 4; ++kk) {
#pragma unroll
    for (int j = 0; j < 8; ++j) {
      int k = kk * 32 + lg * 8 + j;
      xu[kk].e[j] = (bf16_t)(Wau[k * 128 + col] * LOG2E);
      xr[kk].e[j] = (bf16_t)(War[k * 128 + col] * LOG2E);
      xc[kk].e[j] = (bf16_t)(Wac[k * 128 + col] * (2.0f * LOG2E));
      su[kk].e[j] = (bf16_t)(Wbu[k * 128 + col] * LOG2E);
      sr[kk].e[j] = (bf16_t)(Wbr[k * 128 + col] * LOG2E);
      sc[kk].e[j] = (bf16_t)(Wbc[k * 128 + col] * (2.0f * LOG2E));
    }
  }
  const float b_u = bau[col] * LOG2E;
  const float b_r = bar[col] * LOG2E;
  const float b_c = bac[col] * (2.0f * LOG2E);

  // --- att*mask preload (row T_LEN is a pad: duplicate of T_LEN-1, never used)
  for (int idx = tid; idx < (T_LEN + 1) * 16; idx += 512) {
    int t = idx >> 4; if (t > T_LEN - 1) t = T_LEN - 1;
    int row = idx & 15;
    am_lds[idx] = att[t * B_SZ + R0 + row] * mask[(R0 + row) * T_LEN + t];
  }

  // --- fp32 state in registers: lane owns (row = lg*4+i, col)
  float sreg[4];
#pragma unroll
  for (int i = 0; i < 4; ++i)
    sreg[i] = state[(R0 + lg * 4 + i) * 128 + col];

  // state bf16 into sb[0], swizzled layout
  for (int idx = tid; idx < 2048; idx += 512) {
    int row = idx >> 7, k = idx & 127;
    sb[0][(k >> 3) * 128 + (row ^ (2 * ((k >> 3) & 1))) * 8 + (k & 7)] =
        (bf16_t)state[(R0 + row) * 128 + k];
  }

  // --- x staging: thread tid stages row=tid&15, float4 chunk sc4=tid>>4
  const int srow = tid & 15;
  const int sc4  = tid >> 4;
  const int stg_pos = (sc4 >> 1) * 128 + srow * 8 + (sc4 & 1) * 4;  // halfwords
  const float* xrow = x + (size_t)(R0 + srow) * 128 + sc4 * 4;
  const size_t xstep = (size_t)B_SZ * 128;
  const size_t xoff_max = (size_t)(T_LEN - 1) * xstep;

  // prologue: stage x(0), x(1); register-prefetch x(2), x(3)
  {
    float4 v0 = *(const float4*)(xrow);
    float4 v1 = *(const float4*)(xrow + xstep);
    uint2 p0; p0.x = pk_bf16(v0.x, v0.y); p0.y = pk_bf16(v0.z, v0.w);
    uint2 p1; p1.x = pk_bf16(v1.x, v1.y); p1.y = pk_bf16(v1.z, v1.w);
    *(uint2*)&xb[0][stg_pos] = p0;
    *(uint2*)&xb[1][stg_pos] = p1;
  }
  float4 xqA = *(const float4*)(xrow + 2 * xstep);   // x(t+2) for even t
  float4 xqB = *(const float4*)(xrow + 3 * xstep);   // x(t+2) for odd  t
  size_t offA = 4 * xstep;   // next load target for xqA: x(t+4), t even
  size_t offB = 5 * xstep;   // next load target for xqB: x(t+4), t odd

  __syncthreads();   // full drain once

  // x-gates(0) from xb[0] into registers
  f32x4 gU = {b_u, b_u, b_u, b_u};
  f32x4 gR = {b_r, b_r, b_r, b_r};
  f32x4 gC = {b_c, b_c, b_c, b_c};
  {
    bf16x8 ax[4];
#pragma unroll
    for (int kk = 0; kk < 4; ++kk)
      ax[kk] = *(const bf16x8*)&xb[0][kk * 512 + 8 * l];
#pragma unroll
    for (int kk = 0; kk < 4; ++kk) {
      gU = __builtin_amdgcn_mfma_f32_16x16x32_bf16(ax[kk], xu[kk].v, gU, 0, 0, 0);
      gR = __builtin_amdgcn_mfma_f32_16x16x32_bf16(ax[kk], xr[kk].v, gR, 0, 0, 0);
      gC = __builtin_amdgcn_mfma_f32_16x16x32_bf16(ax[kk], xc[kk].v, gC, 0, 0, 0);
    }
  }
  union F4 { float4 v; float e[4]; } amv, amn;
  amv.v = *(const float4*)&am_lds[lg * 4];           // am(0)
  const float* am_ptr = &am_lds[16 + lg * 4];        // walking ptr: am(t+1)

  const int lx8   = 8 * (l ^ (2 * (lg & 1)));        // swizzled sb frag offset
  const int psi   = 2 * ((col >> 3) & 1);            // writer value permutation
  const int wbase = (col >> 3) * 128 + lg * 32 + (col & 7);

  BAR_LDS();   // protect xb[0] before step 0 overwrites it

  // One scan step. xq = x(t+2) register buffer (statically renamed by the
  // caller's 2-step unroll); after staging it, reload it with x(t+4).
  auto step = [&](int t, float4& xq, size_t& xoff) {
    const int rp = t & 1;

    // fragment ds_reads issue FIRST: state frags s(t), then x frags x(t+1)
    bf16x8 as_[4], ax[4];
#pragma unroll
    for (int kk = 0; kk < 4; ++kk)
      as_[kk] = *(const bf16x8*)&sb[rp][kk * 512 + lx8];
#pragma unroll
    for (int kk = 0; kk < 4; ++kk)
      ax[kk]  = *(const bf16x8*)&xb[rp ^ 1][kk * 512 + 8 * l];

    // am(t+1) prefetch early (drains long before the barrier)
    amn.v = *(const float4*)am_ptr;
    am_ptr += 16;

    // stage x(t+2) into xb[rp]; then reload this buffer with x(t+4)
    {
      uint2 p; p.x = pk_bf16(xq.x, xq.y); p.y = pk_bf16(xq.z, xq.w);
      *(uint2*)&xb[rp][stg_pos] = p;
    }
    xq = *(const float4*)(xrow + xoff);
    xoff += 2 * xstep; if (xoff > xoff_max) xoff = xoff_max;

    // state-side MFMAs first (critical path), 4-deep 3-gate interleaved
    // chains (round-0 summation order); then x-side for t+1
    f32x4 aU = gU, aR = gR;
    f32x4 bC = {0.f, 0.f, 0.f, 0.f};
#pragma unroll
    for (int kk = 0; kk < 4; ++kk) {
      aU = __builtin_amdgcn_mfma_f32_16x16x32_bf16(as_[kk], su[kk].v, aU, 0, 0, 0);
      aR = __builtin_amdgcn_mfma_f32_16x16x32_bf16(as_[kk], sr[kk].v, aR, 0, 0, 0);
      bC = __builtin_amdgcn_mfma_f32_16x16x32_bf16(as_[kk], sc[kk].v, bC, 0, 0, 0);
    }
    f32x4 nU = {b_u, b_u, b_u, b_u};
    f32x4 nR = {b_r, b_r, b_r, b_r};
    f32x4 nC = {b_c, b_c, b_c, b_c};
#pragma unroll
    for (int kk = 0; kk < 4; ++kk) {
      nU = __builtin_amdgcn_mfma_f32_16x16x32_bf16(ax[kk], xu[kk].v, nU, 0, 0, 0);
      nR = __builtin_amdgcn_mfma_f32_16x16x32_bf16(ax[kk], xr[kk].v, nR, 0, 0, 0);
      nC = __builtin_amdgcn_mfma_f32_16x16x32_bf16(ax[kk], xc[kk].v, nC, 0, 0, 0);
    }

    bf16_t* wbuf = sb[rp ^ 1];
#pragma unroll
    for (int i = 0; i < 4; ++i) {
      float u  = rcp_f(1.0f + __builtin_amdgcn_exp2f(-aU[i]));
      float r  = rcp_f(1.0f + __builtin_amdgcn_exp2f(-aR[i]));
      float wc = fmaf(r, bC[i], gC[i]);
      float cg = fmaf(-2.0f, rcp_f(__builtin_amdgcn_exp2f(wc) + 1.0f), 1.0f);
      float sf = fmaf(amv.e[i] * u, cg - sreg[i], sreg[i]);
      sreg[i] = sf;
      wbuf[wbase + 8 * (i ^ psi)] = (bf16_t)sf;
    }

    // rotate pipelined registers
    gU = nU; gR = nR; gC = nC;
    amv.v = amn.v;

    BAR_LDS();
  };

#pragma unroll 1
  for (int t = 0; t < T_LEN; t += 2) {
    step(t,     xqA, offA);
    step(t + 1, xqB, offB);
  }

#pragma unroll
  for (int i = 0; i < 4; ++i)
    out[(R0 + lg * 4 + i) * 128 + col] = sreg[i];
}

// ---------------------------------------------------------------------------
extern "C" void kernel_launch(void* const* d_in, const int* in_sizes, int n_in,
                              void* d_out, int out_size, void* d_ws, size_t ws_size,
                              hipStream_t stream)
{
  const float* x    = (const float*)d_in[0];
  const float* st   = (const float*)d_in[1];
  const float* att  = (const float*)d_in[2];
  const float* mask = (const float*)d_in[3];
  // d_in[4] = max_len (unused; shapes hard-coded)
  const float* Wau  = (const float*)d_in[5];
  const float* bau  = (const float*)d_in[6];
  const float* Wbu  = (const float*)d_in[7];
  const float* War  = (const float*)d_in[8];
  const float* bar  = (const float*)d_in[9];
  const float* Wbr  = (const float*)d_in[10];
  const float* Wac  = (const float*)d_in[11];
  const float* bac  = (const float*)d_in[12];
  const float* Wbc  = (const float*)d_in[13];

  (void)d_ws; (void)ws_size;

  augru_fused<<<dim3(64), dim3(512), 0, stream>>>(
      x, st, att, mask, Wau, bau, Wbu, War, bar, Wbr, Wac, bac, Wbc,
      (float*)d_out);
}